// Round 6
// baseline (153.859 us; speedup 1.0000x reference)
//
#include <hip/hip_runtime.h>

#define QDIM 192
#define KDIM 64
#define CDIM 256
#define DOUT 128
#define CAPS 64     // adjacency slots per sub-bucket; per-sub deg ~ Poisson(8)
#define NBCOL 384   // B virtual cols: [U 0:256 | V 256:320 | S 320:384]
#define NEG_INF __int_as_float(0xFF800000)
#define LDP 200     // LDS row pitch in halves (192 + 8 pad)

typedef _Float16 hf2 __attribute__((ext_vector_type(2)));
typedef _Float16 half4 __attribute__((ext_vector_type(4)));
typedef _Float16 half8 __attribute__((ext_vector_type(8)));
typedef float floatx4 __attribute__((ext_vector_type(4)));

#if defined(__has_builtin)
#if __has_builtin(__builtin_amdgcn_fdot2)
#define HAVE_FDOT2 1
#endif
#endif

__device__ __forceinline__ hf2 bc_h2(unsigned u) { return __builtin_bit_cast(hf2, u); }

__device__ __forceinline__ float dot2acc(hf2 a, hf2 b, float c) {
#ifdef HAVE_FDOT2
    return __builtin_amdgcn_fdot2(a, b, c, false);
#else
    return c + (float)a[0] * (float)b[0] + (float)a[1] * (float)b[1];
#endif
}

// prep jobs (all independent):
//  1) query fp32->fp16 into Qh (linear, gemm A-side) AND Pay q-slots
//     (Pay[src] row = 16 lane-chunks of 16 halves: [q l*12..+12 | v l*4..+4])
//  2) GhT: BhT[j][i] = G[i][j] = dot(Wq[i,:], Wk[j,:])  (j<256, i<192) fp16
//  3) direct BhT cols 256..383 from Wv/Ws cols 192..255
//  4) OBall U-part[j][ki] = G[192+ki][j] + (Wk bq)_j = sum_c Wk[j][c]*(Wq[192+ki][c]+bq[c])
//  5) OBall direct (V,S): one-hot row + bias fused
//  6) deg4 init: 0 for masked nodes (binary search), INT_MIN otherwise
__global__ __launch_bounds__(256) void prep_kernel(
        const float* __restrict__ query, _Float16* __restrict__ Qh,
        _Float16* __restrict__ Pay,
        const float* __restrict__ Wq, const float* __restrict__ bq,
        const float* __restrict__ Wk, const float* __restrict__ bk,
        const float* __restrict__ Wv, const float* __restrict__ bv,
        const float* __restrict__ Ws, const float* __restrict__ bs,
        const int* __restrict__ mask, int M,
        _Float16* __restrict__ BhT, float* __restrict__ OBall,
        int* __restrict__ deg4, int qchunks, int N) {
    int t = blockIdx.x * blockDim.x + threadIdx.x;
    if (t < qchunks) {
        float4 v = ((const float4*)query)[t];
        half4 h = { (_Float16)v.x, (_Float16)v.y, (_Float16)v.z, (_Float16)v.w };
        ((half4*)Qh)[t] = h;
        int h0 = t * 4;
        int src = h0 / QDIM, i = h0 - src * QDIM;   // i%12 in {0,4,8}: no chunk straddle
        *(half4*)(Pay + (size_t)src * 256 + (i / 12) * 16 + (i % 12)) = h;
        return;
    }
    t -= qchunks;
    if (t < 256 * QDIM) {                // GhT
        int j = t / QDIM, i = t - j * QDIM;
        const float4* wq = (const float4*)(Wq + (size_t)i * CDIM);
        const float4* wk = (const float4*)(Wk + (size_t)j * CDIM);
        float acc = 0.f;
        #pragma unroll 8
        for (int c = 0; c < 64; c++) {
            float4 a = wq[c], b = wk[c];
            acc += a.x*b.x + a.y*b.y + a.z*b.z + a.w*b.w;
        }
        BhT[(size_t)j * QDIM + i] = (_Float16)acc;
        return;
    }
    t -= 256 * QDIM;
    if (t < 128 * QDIM) {                // direct BhT (V,S)
        int c = t / QDIM, r = t - c * QDIM;
        float val = (c < 64) ? Wv[(size_t)r * CDIM + QDIM + c]
                             : Ws[(size_t)r * CDIM + QDIM + (c - 64)];
        BhT[(size_t)(256 + c) * QDIM + r] = (_Float16)val;
        return;
    }
    t -= 128 * QDIM;
    if (t < 256 * KDIM) {                // OBall U-part
        int j = t >> 6, ki = t & 63;
        const float4* wk  = (const float4*)(Wk + (size_t)j * CDIM);
        const float4* wq  = (const float4*)(Wq + (size_t)(QDIM + ki) * CDIM);
        const float4* bqv = (const float4*)bq;
        float acc = 0.f;
        #pragma unroll 8
        for (int c = 0; c < 64; c++) {
            float4 b = wk[c], a = wq[c], q = bqv[c];
            acc += b.x*(a.x+q.x) + b.y*(a.y+q.y) + b.z*(a.z+q.z) + b.w*(a.w+q.w);
        }
        OBall[(size_t)j * KDIM + ki] = acc;
        return;
    }
    t -= 256 * KDIM;
    if (t < 128 * KDIM) {                // OBall direct (V,S)
        int jj = t >> 6, ki = t & 63;
        const float* Wseg; const float* bseg; int col;
        if (jj < 64) { Wseg = Wv; bseg = bv; col = QDIM + jj; }
        else         { Wseg = Ws; bseg = bs; col = QDIM + (jj - 64); }
        OBall[(size_t)(256 + jj) * KDIM + ki] =
            Wseg[(size_t)(QDIM + ki) * CDIM + col] + bseg[col];
        return;
    }
    t -= 128 * KDIM;
    if (t < 4 * N) {
        int node = t >> 2;
        int lo = 0, hi = M;
        while (lo < hi) { int mid = (lo + hi) >> 1; if (mask[mid] < node) lo = mid + 1; else hi = mid; }
        bool found = (lo < M) && (mask[lo] == node);
        deg4[t] = found ? 0 : (int)0x80000000;
    }
}

// MFMA node GEMM over the reduced col space [U|V|S], 3 block classes:
//  cls 0 (V):  all rows, bn=256 -> Pay v-slots          (157 blocks)
//  cls 1 (U):  masked rows, bn in {0,64,128,192} -> Ubuf (248 blocks)
//  cls 2 (S):  masked rows, bn=320 -> Sbuf               (62 blocks)
// All blocks carry 3 gated edge-scatter slots (atomic post-barrier, adj write
// post-MFMA); adj entry packs (src<<6)|key_idx[src].
__global__ __launch_bounds__(256) void gemm_nodes(
        const _Float16* __restrict__ Qh, const int* __restrict__ key_idx,
        const _Float16* __restrict__ BhT, const float* __restrict__ OBall,
        const int* __restrict__ esrc, const int* __restrict__ edst,
        const int* __restrict__ mask, int M,
        int* deg4, int* __restrict__ adj, int E,
        _Float16* __restrict__ Ubuf, _Float16* __restrict__ Pay,
        float* __restrict__ Sbuf, int N, int XA, int XM) {
    __shared__ __align__(16) _Float16 Bs[64 * LDP];
    int tid = threadIdx.x;
    int b = blockIdx.x;
    int cls, rb, bn;
    if (b < XA)                 { cls = 0; rb = b;                bn = 256; }
    else if (b < XA + 4 * XM)   { int u2 = b - XA; cls = 1; rb = u2 >> 2; bn = (u2 & 3) * 64; }
    else                        { cls = 2; rb = b - XA - 4 * XM;  bn = 320; }
    int bm = rb * 64;

    // scatter duty: 3 gated edge slots (mask-skip via deg4 sign)
    bool doe[3] = {false, false, false};
    int srcv[3]; size_t ci[3] = {0, 0, 0};
    {
        int stride = gridDim.x * 256;
        int base = b * 256 + tid;
        #pragma unroll
        for (int q = 0; q < 3; q++) {
            int e = base + q * stride;
            if (e < E) {
                int d = edst[e];
                size_t c = (size_t)d * 4 + (e & 3);
                if (deg4[c] >= 0) {
                    doe[q] = true;
                    int s = esrc[e];
                    srcv[q] = (s << 6) | (key_idx[s] & 63);
                    ci[q] = c;
                }
            }
        }
    }

    int w = tid >> 6, l = tid & 63;
    int lrow = l & 15, quad = l >> 4;

    // A fragments direct from global (issued pre-barrier; drain during Bs staging)
    int ra = w * 16 + lrow;
    int gra = (cls == 0) ? min(bm + ra, N - 1) : mask[min(bm + ra, M - 1)];
    const _Float16* abase = Qh + (size_t)gra * QDIM + quad * 8;
    half8 af[6];
    #pragma unroll
    for (int ks = 0; ks < 6; ks++) af[ks] = *(const half8*)(abase + ks * 32);

    // B tile: 64 cols x 192 halves = 1536 uint4; 6 per thread
    #pragma unroll
    for (int it = 0; it < 6; it++) {
        int idx = tid + it * 256;
        int cc = idx / 24, q4 = idx % 24;
        uint4 vb = ((const uint4*)(BhT + (size_t)(bn + cc) * QDIM))[q4];
        *((uint4*)&Bs[cc * LDP + q4 * 8]) = vb;
    }
    __syncthreads();

    // contended atomics now; latency hides under ds_read+MFMA below
    int slot[3] = {-1, -1, -1};
    #pragma unroll
    for (int q = 0; q < 3; q++) if (doe[q]) slot[q] = atomicAdd(&deg4[ci[q]], 1);

    floatx4 acc[4] = {{0.f,0.f,0.f,0.f},{0.f,0.f,0.f,0.f},{0.f,0.f,0.f,0.f},{0.f,0.f,0.f,0.f}};
    #pragma unroll
    for (int ks = 0; ks < 6; ks++) {
        #pragma unroll
        for (int nt = 0; nt < 4; nt++) {
            half8 bf = *(const half8*)(&Bs[(nt * 16 + lrow) * LDP + quad * 8 + ks * 32]);
            acc[nt] = __builtin_amdgcn_mfma_f32_16x16x32_f16(af[ks], bf, acc[nt], 0, 0, 0);
        }
    }

    // consume atomic results only now (waitcnt lands after the MFMAs)
    #pragma unroll
    for (int q = 0; q < 3; q++)
        if (doe[q] && (unsigned)slot[q] < CAPS) adj[ci[q] * CAPS + slot[q]] = srcv[q];

    // epilogue: clamped/duplicate rows write identical values (benign)
    int ki[4], grs[4];
    #pragma unroll
    for (int reg = 0; reg < 4; reg++) {
        int re = w * 16 + quad * 4 + reg;
        grs[reg] = (cls == 0) ? min(bm + re, N - 1) : mask[min(bm + re, M - 1)];
        ki[reg] = key_idx[grs[reg]];
    }
    #pragma unroll
    for (int nt = 0; nt < 4; nt++) {
        int gc = bn + nt * 16 + lrow;
        const float* obc = OBall + (size_t)gc * KDIM;
        #pragma unroll
        for (int reg = 0; reg < 4; reg++) {
            int gr = grs[reg];
            float v = acc[nt][reg] + obc[ki[reg]];
            if (gc < 256)      Ubuf[(size_t)gr * 256 + gc] = (_Float16)v;
            else if (gc < 320) { int c = gc - 256;
                                 Pay[(size_t)gr * 256 + (c >> 2) * 16 + 12 + (c & 3)] = (_Float16)v; }
            else               Sbuf[(size_t)gr * KDIM + (gc - 320)] = v;
        }
    }
}

// 1 wave per output-run (masked node). score = (u·x_s)/16 with the dst-constant
// terms dropped (softmax-invariant): per edge, ONE payload gather (2x uint4,
// interleaved q|v) + tiny per-node lut read u[192+ks] (256B, L1). 4 sub-buckets
// walked as one concatenated list round-robin (balanced); 2-deep register
// pipeline; online softmax per group; single end-merge; fused relu + GEMV.
__global__ __launch_bounds__(256) void attend_out(
        const _Float16* __restrict__ Ubuf, const _Float16* __restrict__ Pay,
        const float* __restrict__ Sbuf,
        const int* __restrict__ deg4, const int* __restrict__ adj,
        const int* __restrict__ mask, const float* __restrict__ Wo,
        const float* __restrict__ bo, float* __restrict__ out, int M) {
    int w = threadIdx.x >> 6, lane = threadIdx.x & 63;
    int r = blockIdx.x * 4 + w;
    if (r >= M) return;
    int node = mask[r];
    if (r > 0 && mask[r - 1] == node) return;   // duplicate run: start-wave writes it
    int l = lane & 15, g = lane >> 4;

    // u fragment: halves [l*12, l*12+12)
    const uint2* up = (const uint2*)(Ubuf + (size_t)node * 256 + l * 12);
    uint2 u0 = up[0], u1 = up[1], u2 = up[2];
    hf2 uf[6] = { bc_h2(u0.x), bc_h2(u0.y), bc_h2(u1.x),
                  bc_h2(u1.y), bc_h2(u2.x), bc_h2(u2.y) };
    const _Float16* lutp = Ubuf + (size_t)node * 256 + QDIM;

    // concatenated-list geometry over 4 sub-buckets
    int dn_g = min(deg4[(size_t)node * 4 + g], CAPS);
    int d0 = __shfl(dn_g, 0, 64), d1 = __shfl(dn_g, 16, 64);
    int d2 = __shfl(dn_g, 32, 64), d3 = __shfl(dn_g, 48, 64);
    int O1 = d0, O2 = d0 + d1, O3 = d0 + d1 + d2, T = O3 + d3;
    const size_t base4 = (size_t)node * 4 * CAPS;
    auto fs = [&](int j) -> int {
        int b = (j >= O1) + (j >= O2) + (j >= O3);
        int off = j - (b == 0 ? 0 : b == 1 ? O1 : b == 2 ? O2 : O3);
        return adj[base4 + (size_t)b * CAPS + off];   // packed (src<<6)|ks
    };
    auto idxAt = [&](int p) -> int { return fs(min(g + 4 * p, T - 1)); };

    float m = NEG_INF, dsum = 0.f;
    float a0 = 0.f, a1 = 0.f, a2 = 0.f, a3 = 0.f;

    auto compute = [&](uint4 A0, uint4 A1, float lut) {
        float d = 0.f;
        d = dot2acc(bc_h2(A0.x), uf[0], d);
        d = dot2acc(bc_h2(A0.y), uf[1], d);
        d = dot2acc(bc_h2(A0.z), uf[2], d);
        d = dot2acc(bc_h2(A0.w), uf[3], d);
        d = dot2acc(bc_h2(A1.x), uf[4], d);
        d = dot2acc(bc_h2(A1.y), uf[5], d);
        d += __shfl_xor(d, 1, 64);
        d += __shfl_xor(d, 2, 64);
        d += __shfl_xor(d, 4, 64);
        d += __shfl_xor(d, 8, 64);
        float sc = (d + lut) * 0.0625f;      // 1/sqrt(256); dst-const terms dropped
        float m_new = fmaxf(m, sc);
        float scale = __expf(m - m_new);     // first edge: exp(-inf)=0
        float p = __expf(sc - m_new);
        dsum = dsum * scale + p;
        hf2 v01 = bc_h2(A1.z), v23 = bc_h2(A1.w);
        a0 = a0 * scale + p * (float)v01[0];
        a1 = a1 * scale + p * (float)v01[1];
        a2 = a2 * scale + p * (float)v23[0];
        a3 = a3 * scale + p * (float)v23[1];
        m = m_new;
    };

    int np = (g < T) ? ((T - g + 3) >> 2) : 0;   // positions for this group
    uint4 A0 = {}, A1 = {}, B0 = {}, B1 = {};
    float lutA = 0.f, lutB = 0.f;
    int vC = 0, vD = 0;
    if (np > 0) {
        int vA = idxAt(0);
        const uint4* pp = (const uint4*)(Pay + (size_t)(vA >> 6) * 256 + l * 16);
        A0 = pp[0]; A1 = pp[1];
        lutA = (float)lutp[vA & 63];
        int vB = idxAt(1);
        const uint4* pb = (const uint4*)(Pay + (size_t)(vB >> 6) * 256 + l * 16);
        B0 = pb[0]; B1 = pb[1];
        lutB = (float)lutp[vB & 63];
        vC = idxAt(2); vD = idxAt(3);
    }
    for (int p = 0; p < np; p += 2) {
        compute(A0, A1, lutA);                 // position p
        {   // refill A <- position p+2 (clamped-valid speculative load)
            const uint4* pp = (const uint4*)(Pay + (size_t)(vC >> 6) * 256 + l * 16);
            A0 = pp[0]; A1 = pp[1];
            lutA = (float)lutp[vC & 63];
        }
        int vC2 = idxAt(p + 4);
        if (p + 1 < np) compute(B0, B1, lutB); // position p+1
        {   // refill B <- position p+3
            const uint4* pb = (const uint4*)(Pay + (size_t)(vD >> 6) * 256 + l * 16);
            B0 = pb[0]; B1 = pb[1];
            lutB = (float)lutp[vD & 63];
        }
        int vD2 = idxAt(p + 5);
        vC = vC2; vD = vD2;
    }

    // merge the 4 groups (m, dsum group-uniform)
    float Mx = fmaxf(m, __shfl_xor(m, 16, 64));
    Mx = fmaxf(Mx, __shfl_xor(Mx, 32, 64));
    float wgt = (m == NEG_INF) ? 0.f : __expf(m - Mx);   // empty group / T==0
    float ds = dsum * wgt;
    ds += __shfl_xor(ds, 16, 64);
    ds += __shfl_xor(ds, 32, 64);
    a0 *= wgt; a1 *= wgt; a2 *= wgt; a3 *= wgt;
    a0 += __shfl_xor(a0, 16, 64); a0 += __shfl_xor(a0, 32, 64);
    a1 += __shfl_xor(a1, 16, 64); a1 += __shfl_xor(a1, 32, 64);
    a2 += __shfl_xor(a2, 16, 64); a2 += __shfl_xor(a2, 32, 64);
    a3 += __shfl_xor(a3, 16, 64); a3 += __shfl_xor(a3, 32, 64);
    float inv = 1.f / (ds + 1e-16f);

    // h cols l*4..l*4+3 (identical across groups)
    float4 s4 = *((const float4*)(Sbuf + (size_t)node * KDIM + l * 4));
    float h0 = fmaxf(a0 * inv + s4.x, 0.f);
    float h1 = fmaxf(a1 * inv + s4.y, 0.f);
    float h2 = fmaxf(a2 * inv + s4.z, 0.f);
    float h3 = fmaxf(a3 * inv + s4.w, 0.f);

    // GEMV: out(row) = h @ Wo + bo
    float o0 = bo[lane], o1 = bo[lane + 64];
    #pragma unroll
    for (int c = 0; c < KDIM; c++) {
        float hc = (c & 3) == 0 ? h0 : (c & 3) == 1 ? h1 : (c & 3) == 2 ? h2 : h3;
        float hv = __shfl(hc, c >> 2, 64);
        o0 += hv * Wo[c * DOUT + lane];
        o1 += hv * Wo[c * DOUT + 64 + lane];
    }
    int rr = r;
    do {
        out[(size_t)rr * DOUT + lane] = o0;
        out[(size_t)rr * DOUT + 64 + lane] = o1;
        rr++;
    } while (rr < M && mask[rr] == node);
}

extern "C" void kernel_launch(void* const* d_in, const int* in_sizes, int n_in,
                              void* d_out, int out_size, void* d_ws, size_t ws_size,
                              hipStream_t stream) {
    const float* query    = (const float*)d_in[0];
    const int* key_idx    = (const int*)d_in[1];
    const int* edge_index = (const int*)d_in[2];
    const int* mask_idx   = (const int*)d_in[3];
    const float* Wq = (const float*)d_in[4];
    const float* bq = (const float*)d_in[5];
    const float* Wk = (const float*)d_in[6];
    const float* bk = (const float*)d_in[7];
    const float* Wv = (const float*)d_in[8];
    const float* bv = (const float*)d_in[9];
    const float* Ws = (const float*)d_in[10];
    const float* bs = (const float*)d_in[11];
    const float* Wo = (const float*)d_in[12];
    const float* bo = (const float*)d_in[13];
    (void)bk;   // bk folds out: its dst-side terms are softmax-invariant

    int N = in_sizes[0] / QDIM;
    int E = in_sizes[2] / 2;
    int M = in_sizes[3];
    const int* esrc = edge_index;
    const int* edst = edge_index + E;

    char* wsb = (char*)d_ws;
    size_t off = 0;
    auto alloc = [&](size_t nbytes) { char* p = wsb + off; off += (nbytes + 15) & ~15ull; return p; };
    _Float16* Qh   = (_Float16*)alloc((size_t)N * QDIM * 2);
    _Float16* Pay  = (_Float16*)alloc((size_t)N * 256 * 2);
    _Float16* Ubuf = (_Float16*)alloc((size_t)N * 256 * 2);
    _Float16* BhT  = (_Float16*)alloc((size_t)NBCOL * QDIM * 2);
    float* OBall   = (float*)alloc((size_t)NBCOL * KDIM * 4);
    float* Sbuf    = (float*)alloc((size_t)N * KDIM * 4);
    int*   deg4    = (int*)alloc((size_t)N * 4 * 4);
    int*   adj     = (int*)alloc((size_t)N * 4 * CAPS * 4);

    int qchunks = N * QDIM / 4;   // float4 chunks of query
    int total1 = qchunks + 256 * QDIM + 128 * QDIM + 256 * KDIM + 128 * KDIM + 4 * N;
    prep_kernel<<<(total1 + 255) / 256, 256, 0, stream>>>(
        query, Qh, Pay, Wq, bq, Wk, bk, Wv, bv, Ws, bs, mask_idx, M,
        BhT, OBall, deg4, qchunks, N);

    int XA = (N + 63) / 64, XM = (M + 63) / 64;
    int NB = XA + 4 * XM + XM;    // V(157) + U(248) + S(62) = 467
    gemm_nodes<<<NB, 256, 0, stream>>>(Qh, key_idx, BhT, OBall, esrc, edst,
                                       mask_idx, M, deg4, adj, E,
                                       Ubuf, Pay, Sbuf, N, XA, XM);

    attend_out<<<(M + 3) / 4, 256, 0, stream>>>(Ubuf, Pay, Sbuf, deg4, adj,
                                                mask_idx, Wo, bo, (float*)d_out, M);
}

// Round 7
// 129.464 us; speedup vs baseline: 1.1884x; 1.1884x over previous
//
#include <hip/hip_runtime.h>

#define QDIM 192
#define KDIM 64
#define CDIM 256
#define DOUT 128
#define CAPS 64     // adjacency slots per sub-bucket; per-sub deg ~ Poisson(8)
#define NBCOL 384   // B virtual cols: [U 0:256 | V 256:320 | S 320:384]
#define NEG_INF __int_as_float(0xFF800000)
#define LDP 200     // LDS row pitch in halves (192 + 8 pad)
#define GBLK 4096   // wave-parallel G-region blocks (256 j x 64 wave-jobs / 4 waves per block)

typedef _Float16 hf2 __attribute__((ext_vector_type(2)));
typedef _Float16 half4 __attribute__((ext_vector_type(4)));
typedef _Float16 half8 __attribute__((ext_vector_type(8)));
typedef float floatx4 __attribute__((ext_vector_type(4)));

#if defined(__has_builtin)
#if __has_builtin(__builtin_amdgcn_fdot2)
#define HAVE_FDOT2 1
#endif
#endif

__device__ __forceinline__ hf2 bc_h2(unsigned u) { return __builtin_bit_cast(hf2, u); }

__device__ __forceinline__ float dot2acc(hf2 a, hf2 b, float c) {
#ifdef HAVE_FDOT2
    return __builtin_amdgcn_fdot2(a, b, c, false);
#else
    return c + (float)a[0] * (float)b[0] + (float)a[1] * (float)b[1];
#endif
}

__device__ __forceinline__ float wave_sum(float p) {
    p += __shfl_xor(p, 1, 64);
    p += __shfl_xor(p, 2, 64);
    p += __shfl_xor(p, 4, 64);
    p += __shfl_xor(p, 8, 64);
    p += __shfl_xor(p, 16, 64);
    p += __shfl_xor(p, 32, 64);
    return p;
}

// prep, restructured after R6's latency stall:
//  Region G (blocks [0, GBLK)): WAVE-PARALLEL dots along K.
//    wave job gw = (blk*4 + wid); j = gw>>6, sub = gw&63.
//    lane c holds float4 at offset 4c of each 256-wide row (coalesced 1KB loads).
//    sub<48:  GhT[j][sub*4 .. +4)   = fp16( Wq[i,:] . Wk[j,:] )
//    sub>=48: OBall[j][k0 .. +4)    = (Wq[192+ki,:]+bq) . Wk[j,:]   (f32)
//    Wk row loaded ONCE per wave, reused for 4 outputs; 6-stage shfl butterfly.
//  Region T (linear threads after GBLK):
//    1) query fp32->fp16 into Qh AND Pay q-slots
//    2) direct BhT cols 256..383 from Wv/Ws cols 192..255
//    3) OBall direct (V,S): one-hot row + bias fused
//    4) deg4 init: 0 for masked nodes (binary search), INT_MIN otherwise
__global__ __launch_bounds__(256) void prep_kernel(
        const float* __restrict__ query, _Float16* __restrict__ Qh,
        _Float16* __restrict__ Pay,
        const float* __restrict__ Wq, const float* __restrict__ bq,
        const float* __restrict__ Wk, const float* __restrict__ bk,
        const float* __restrict__ Wv, const float* __restrict__ bv,
        const float* __restrict__ Ws, const float* __restrict__ bs,
        const int* __restrict__ mask, int M,
        _Float16* __restrict__ BhT, float* __restrict__ OBall,
        int* __restrict__ deg4, int qchunks, int N) {
    int blk = blockIdx.x;
    if (blk < GBLK) {
        int lane = threadIdx.x & 63;
        int gw = blk * 4 + (threadIdx.x >> 6);
        int j = gw >> 6, sub = gw & 63;
        float4 wk4 = ((const float4*)(Wk + (size_t)j * CDIM))[lane];
        if (sub < 48) {
            half4 h;
            #pragma unroll
            for (int r = 0; r < 4; r++) {
                int i = sub * 4 + r;
                float4 a = ((const float4*)(Wq + (size_t)i * CDIM))[lane];
                float p = a.x*wk4.x + a.y*wk4.y + a.z*wk4.z + a.w*wk4.w;
                h[r] = (_Float16)wave_sum(p);
            }
            if (lane == 0) *(half4*)(BhT + (size_t)j * QDIM + sub * 4) = h;
        } else {
            int k0 = (sub - 48) * 4;
            float rr[4];
            float4 b4 = ((const float4*)bq)[lane];
            #pragma unroll
            for (int r = 0; r < 4; r++) {
                int i = QDIM + k0 + r;
                float4 a = ((const float4*)(Wq + (size_t)i * CDIM))[lane];
                float p = (a.x+b4.x)*wk4.x + (a.y+b4.y)*wk4.y
                        + (a.z+b4.z)*wk4.z + (a.w+b4.w)*wk4.w;
                rr[r] = wave_sum(p);
            }
            if (lane == 0)
                *(float4*)(OBall + (size_t)j * KDIM + k0) = make_float4(rr[0], rr[1], rr[2], rr[3]);
        }
        return;
    }
    int t = (blk - GBLK) * 256 + threadIdx.x;
    if (t < qchunks) {
        float4 v = ((const float4*)query)[t];
        half4 h = { (_Float16)v.x, (_Float16)v.y, (_Float16)v.z, (_Float16)v.w };
        ((half4*)Qh)[t] = h;
        int h0 = t * 4;
        int src = h0 / QDIM, i = h0 - src * QDIM;   // i%12 in {0,4,8}: no chunk straddle
        *(half4*)(Pay + (size_t)src * 256 + (i / 12) * 16 + (i % 12)) = h;
        return;
    }
    t -= qchunks;
    if (t < 128 * QDIM) {                // direct BhT (V,S)
        int c = t / QDIM, r = t - c * QDIM;
        float val = (c < 64) ? Wv[(size_t)r * CDIM + QDIM + c]
                             : Ws[(size_t)r * CDIM + QDIM + (c - 64)];
        BhT[(size_t)(256 + c) * QDIM + r] = (_Float16)val;
        return;
    }
    t -= 128 * QDIM;
    if (t < 128 * KDIM) {                // OBall direct (V,S)
        int jj = t >> 6, ki = t & 63;
        const float* Wseg; const float* bseg; int col;
        if (jj < 64) { Wseg = Wv; bseg = bv; col = QDIM + jj; }
        else         { Wseg = Ws; bseg = bs; col = QDIM + (jj - 64); }
        OBall[(size_t)(256 + jj) * KDIM + ki] =
            Wseg[(size_t)(QDIM + ki) * CDIM + col] + bseg[col];
        return;
    }
    t -= 128 * KDIM;
    if (t < 4 * N) {
        int node = t >> 2;
        int lo = 0, hi = M;
        while (lo < hi) { int mid = (lo + hi) >> 1; if (mask[mid] < node) lo = mid + 1; else hi = mid; }
        bool found = (lo < M) && (mask[lo] == node);
        deg4[t] = found ? 0 : (int)0x80000000;
    }
}

// MFMA node GEMM over the reduced col space [U|V|S], 3 block classes:
//  cls 0 (V):  all rows, bn=256 -> Pay v-slots          (157 blocks)
//  cls 1 (U):  masked rows, bn in {0,64,128,192} -> Ubuf (248 blocks)
//  cls 2 (S):  masked rows, bn=320 -> Sbuf               (62 blocks)
// All blocks carry 3 gated edge-scatter slots (atomic post-barrier, adj write
// post-MFMA); adj entry packs (src<<6)|key_idx[src].
__global__ __launch_bounds__(256) void gemm_nodes(
        const _Float16* __restrict__ Qh, const int* __restrict__ key_idx,
        const _Float16* __restrict__ BhT, const float* __restrict__ OBall,
        const int* __restrict__ esrc, const int* __restrict__ edst,
        const int* __restrict__ mask, int M,
        int* deg4, int* __restrict__ adj, int E,
        _Float16* __restrict__ Ubuf, _Float16* __restrict__ Pay,
        float* __restrict__ Sbuf, int N, int XA, int XM) {
    __shared__ __align__(16) _Float16 Bs[64 * LDP];
    int tid = threadIdx.x;
    int b = blockIdx.x;
    int cls, rb, bn;
    if (b < XA)                 { cls = 0; rb = b;                bn = 256; }
    else if (b < XA + 4 * XM)   { int u2 = b - XA; cls = 1; rb = u2 >> 2; bn = (u2 & 3) * 64; }
    else                        { cls = 2; rb = b - XA - 4 * XM;  bn = 320; }
    int bm = rb * 64;

    // scatter duty: 3 gated edge slots (mask-skip via deg4 sign)
    bool doe[3] = {false, false, false};
    int srcv[3]; size_t ci[3] = {0, 0, 0};
    {
        int stride = gridDim.x * 256;
        int base = b * 256 + tid;
        #pragma unroll
        for (int q = 0; q < 3; q++) {
            int e = base + q * stride;
            if (e < E) {
                int d = edst[e];
                size_t c = (size_t)d * 4 + (e & 3);
                if (deg4[c] >= 0) {
                    doe[q] = true;
                    int s = esrc[e];
                    srcv[q] = (s << 6) | (key_idx[s] & 63);
                    ci[q] = c;
                }
            }
        }
    }

    int w = tid >> 6, l = tid & 63;
    int lrow = l & 15, quad = l >> 4;

    // A fragments direct from global (issued pre-barrier; drain during Bs staging)
    int ra = w * 16 + lrow;
    int gra = (cls == 0) ? min(bm + ra, N - 1) : mask[min(bm + ra, M - 1)];
    const _Float16* abase = Qh + (size_t)gra * QDIM + quad * 8;
    half8 af[6];
    #pragma unroll
    for (int ks = 0; ks < 6; ks++) af[ks] = *(const half8*)(abase + ks * 32);

    // B tile: 64 cols x 192 halves = 1536 uint4; 6 per thread
    #pragma unroll
    for (int it = 0; it < 6; it++) {
        int idx = tid + it * 256;
        int cc = idx / 24, q4 = idx % 24;
        uint4 vb = ((const uint4*)(BhT + (size_t)(bn + cc) * QDIM))[q4];
        *((uint4*)&Bs[cc * LDP + q4 * 8]) = vb;
    }
    __syncthreads();

    // contended atomics now; latency hides under ds_read+MFMA below
    int slot[3] = {-1, -1, -1};
    #pragma unroll
    for (int q = 0; q < 3; q++) if (doe[q]) slot[q] = atomicAdd(&deg4[ci[q]], 1);

    floatx4 acc[4] = {{0.f,0.f,0.f,0.f},{0.f,0.f,0.f,0.f},{0.f,0.f,0.f,0.f},{0.f,0.f,0.f,0.f}};
    #pragma unroll
    for (int ks = 0; ks < 6; ks++) {
        #pragma unroll
        for (int nt = 0; nt < 4; nt++) {
            half8 bf = *(const half8*)(&Bs[(nt * 16 + lrow) * LDP + quad * 8 + ks * 32]);
            acc[nt] = __builtin_amdgcn_mfma_f32_16x16x32_f16(af[ks], bf, acc[nt], 0, 0, 0);
        }
    }

    // consume atomic results only now (waitcnt lands after the MFMAs)
    #pragma unroll
    for (int q = 0; q < 3; q++)
        if (doe[q] && (unsigned)slot[q] < CAPS) adj[ci[q] * CAPS + slot[q]] = srcv[q];

    // epilogue: clamped/duplicate rows write identical values (benign)
    int ki[4], grs[4];
    #pragma unroll
    for (int reg = 0; reg < 4; reg++) {
        int re = w * 16 + quad * 4 + reg;
        grs[reg] = (cls == 0) ? min(bm + re, N - 1) : mask[min(bm + re, M - 1)];
        ki[reg] = key_idx[grs[reg]];
    }
    #pragma unroll
    for (int nt = 0; nt < 4; nt++) {
        int gc = bn + nt * 16 + lrow;
        const float* obc = OBall + (size_t)gc * KDIM;
        #pragma unroll
        for (int reg = 0; reg < 4; reg++) {
            int gr = grs[reg];
            float v = acc[nt][reg] + obc[ki[reg]];
            if (gc < 256)      Ubuf[(size_t)gr * 256 + gc] = (_Float16)v;
            else if (gc < 320) { int c = gc - 256;
                                 Pay[(size_t)gr * 256 + (c >> 2) * 16 + 12 + (c & 3)] = (_Float16)v; }
            else               Sbuf[(size_t)gr * KDIM + (gc - 320)] = v;
        }
    }
}

// 1 wave per output-run (masked node). score = (u.x_s)/16 with the dst-constant
// terms dropped (softmax-invariant): per edge, ONE payload gather (2x uint4,
// interleaved q|v) + tiny per-node lut read u[192+ks] (256B, L1). 4 sub-buckets
// walked as one concatenated list round-robin (balanced); 2-deep register
// pipeline; online softmax per group; single end-merge; fused relu + GEMV.
__global__ __launch_bounds__(256) void attend_out(
        const _Float16* __restrict__ Ubuf, const _Float16* __restrict__ Pay,
        const float* __restrict__ Sbuf,
        const int* __restrict__ deg4, const int* __restrict__ adj,
        const int* __restrict__ mask, const float* __restrict__ Wo,
        const float* __restrict__ bo, float* __restrict__ out, int M) {
    int w = threadIdx.x >> 6, lane = threadIdx.x & 63;
    int r = blockIdx.x * 4 + w;
    if (r >= M) return;
    int node = mask[r];
    if (r > 0 && mask[r - 1] == node) return;   // duplicate run: start-wave writes it
    int l = lane & 15, g = lane >> 4;

    // u fragment: halves [l*12, l*12+12)
    const uint2* up = (const uint2*)(Ubuf + (size_t)node * 256 + l * 12);
    uint2 u0 = up[0], u1 = up[1], u2 = up[2];
    hf2 uf[6] = { bc_h2(u0.x), bc_h2(u0.y), bc_h2(u1.x),
                  bc_h2(u1.y), bc_h2(u2.x), bc_h2(u2.y) };
    const _Float16* lutp = Ubuf + (size_t)node * 256 + QDIM;

    // concatenated-list geometry over 4 sub-buckets
    int dn_g = min(deg4[(size_t)node * 4 + g], CAPS);
    int d0 = __shfl(dn_g, 0, 64), d1 = __shfl(dn_g, 16, 64);
    int d2 = __shfl(dn_g, 32, 64), d3 = __shfl(dn_g, 48, 64);
    int O1 = d0, O2 = d0 + d1, O3 = d0 + d1 + d2, T = O3 + d3;
    const size_t base4 = (size_t)node * 4 * CAPS;
    auto fs = [&](int j) -> int {
        int b = (j >= O1) + (j >= O2) + (j >= O3);
        int off = j - (b == 0 ? 0 : b == 1 ? O1 : b == 2 ? O2 : O3);
        return adj[base4 + (size_t)b * CAPS + off];   // packed (src<<6)|ks
    };
    auto idxAt = [&](int p) -> int { return fs(min(g + 4 * p, T - 1)); };

    float m = NEG_INF, dsum = 0.f;
    float a0 = 0.f, a1 = 0.f, a2 = 0.f, a3 = 0.f;

    auto compute = [&](uint4 A0, uint4 A1, float lut) {
        float d = 0.f;
        d = dot2acc(bc_h2(A0.x), uf[0], d);
        d = dot2acc(bc_h2(A0.y), uf[1], d);
        d = dot2acc(bc_h2(A0.z), uf[2], d);
        d = dot2acc(bc_h2(A0.w), uf[3], d);
        d = dot2acc(bc_h2(A1.x), uf[4], d);
        d = dot2acc(bc_h2(A1.y), uf[5], d);
        d += __shfl_xor(d, 1, 64);
        d += __shfl_xor(d, 2, 64);
        d += __shfl_xor(d, 4, 64);
        d += __shfl_xor(d, 8, 64);
        float sc = (d + lut) * 0.0625f;      // 1/sqrt(256); dst-const terms dropped
        float m_new = fmaxf(m, sc);
        float scale = __expf(m - m_new);     // first edge: exp(-inf)=0
        float p = __expf(sc - m_new);
        dsum = dsum * scale + p;
        hf2 v01 = bc_h2(A1.z), v23 = bc_h2(A1.w);
        a0 = a0 * scale + p * (float)v01[0];
        a1 = a1 * scale + p * (float)v01[1];
        a2 = a2 * scale + p * (float)v23[0];
        a3 = a3 * scale + p * (float)v23[1];
        m = m_new;
    };

    int np = (g < T) ? ((T - g + 3) >> 2) : 0;   // positions for this group
    uint4 A0 = {}, A1 = {}, B0 = {}, B1 = {};
    float lutA = 0.f, lutB = 0.f;
    int vC = 0, vD = 0;
    if (np > 0) {
        int vA = idxAt(0);
        const uint4* pp = (const uint4*)(Pay + (size_t)(vA >> 6) * 256 + l * 16);
        A0 = pp[0]; A1 = pp[1];
        lutA = (float)lutp[vA & 63];
        int vB = idxAt(1);
        const uint4* pb = (const uint4*)(Pay + (size_t)(vB >> 6) * 256 + l * 16);
        B0 = pb[0]; B1 = pb[1];
        lutB = (float)lutp[vB & 63];
        vC = idxAt(2); vD = idxAt(3);
    }
    for (int p = 0; p < np; p += 2) {
        compute(A0, A1, lutA);                 // position p
        {   // refill A <- position p+2 (clamped-valid speculative load)
            const uint4* pp = (const uint4*)(Pay + (size_t)(vC >> 6) * 256 + l * 16);
            A0 = pp[0]; A1 = pp[1];
            lutA = (float)lutp[vC & 63];
        }
        int vC2 = idxAt(p + 4);
        if (p + 1 < np) compute(B0, B1, lutB); // position p+1
        {   // refill B <- position p+3
            const uint4* pb = (const uint4*)(Pay + (size_t)(vD >> 6) * 256 + l * 16);
            B0 = pb[0]; B1 = pb[1];
            lutB = (float)lutp[vD & 63];
        }
        int vD2 = idxAt(p + 5);
        vC = vC2; vD = vD2;
    }

    // merge the 4 groups (m, dsum group-uniform)
    float Mx = fmaxf(m, __shfl_xor(m, 16, 64));
    Mx = fmaxf(Mx, __shfl_xor(Mx, 32, 64));
    float wgt = (m == NEG_INF) ? 0.f : __expf(m - Mx);   // empty group / T==0
    float ds = dsum * wgt;
    ds += __shfl_xor(ds, 16, 64);
    ds += __shfl_xor(ds, 32, 64);
    a0 *= wgt; a1 *= wgt; a2 *= wgt; a3 *= wgt;
    a0 += __shfl_xor(a0, 16, 64); a0 += __shfl_xor(a0, 32, 64);
    a1 += __shfl_xor(a1, 16, 64); a1 += __shfl_xor(a1, 32, 64);
    a2 += __shfl_xor(a2, 16, 64); a2 += __shfl_xor(a2, 32, 64);
    a3 += __shfl_xor(a3, 16, 64); a3 += __shfl_xor(a3, 32, 64);
    float inv = 1.f / (ds + 1e-16f);

    // h cols l*4..l*4+3 (identical across groups)
    float4 s4 = *((const float4*)(Sbuf + (size_t)node * KDIM + l * 4));
    float h0 = fmaxf(a0 * inv + s4.x, 0.f);
    float h1 = fmaxf(a1 * inv + s4.y, 0.f);
    float h2 = fmaxf(a2 * inv + s4.z, 0.f);
    float h3 = fmaxf(a3 * inv + s4.w, 0.f);

    // GEMV: out(row) = h @ Wo + bo
    float o0 = bo[lane], o1 = bo[lane + 64];
    #pragma unroll
    for (int c = 0; c < KDIM; c++) {
        float hc = (c & 3) == 0 ? h0 : (c & 3) == 1 ? h1 : (c & 3) == 2 ? h2 : h3;
        float hv = __shfl(hc, c >> 2, 64);
        o0 += hv * Wo[c * DOUT + lane];
        o1 += hv * Wo[c * DOUT + 64 + lane];
    }
    int rr = r;
    do {
        out[(size_t)rr * DOUT + lane] = o0;
        out[(size_t)rr * DOUT + 64 + lane] = o1;
        rr++;
    } while (rr < M && mask[rr] == node);
}

extern "C" void kernel_launch(void* const* d_in, const int* in_sizes, int n_in,
                              void* d_out, int out_size, void* d_ws, size_t ws_size,
                              hipStream_t stream) {
    const float* query    = (const float*)d_in[0];
    const int* key_idx    = (const int*)d_in[1];
    const int* edge_index = (const int*)d_in[2];
    const int* mask_idx   = (const int*)d_in[3];
    const float* Wq = (const float*)d_in[4];
    const float* bq = (const float*)d_in[5];
    const float* Wk = (const float*)d_in[6];
    const float* bk = (const float*)d_in[7];
    const float* Wv = (const float*)d_in[8];
    const float* bv = (const float*)d_in[9];
    const float* Ws = (const float*)d_in[10];
    const float* bs = (const float*)d_in[11];
    const float* Wo = (const float*)d_in[12];
    const float* bo = (const float*)d_in[13];
    (void)bk;   // bk folds out: its dst-side terms are softmax-invariant

    int N = in_sizes[0] / QDIM;
    int E = in_sizes[2] / 2;
    int M = in_sizes[3];
    const int* esrc = edge_index;
    const int* edst = edge_index + E;

    char* wsb = (char*)d_ws;
    size_t off = 0;
    auto alloc = [&](size_t nbytes) { char* p = wsb + off; off += (nbytes + 15) & ~15ull; return p; };
    _Float16* Qh   = (_Float16*)alloc((size_t)N * QDIM * 2);
    _Float16* Pay  = (_Float16*)alloc((size_t)N * 256 * 2);
    _Float16* Ubuf = (_Float16*)alloc((size_t)N * 256 * 2);
    _Float16* BhT  = (_Float16*)alloc((size_t)NBCOL * QDIM * 2);
    float* OBall   = (float*)alloc((size_t)NBCOL * KDIM * 4);
    float* Sbuf    = (float*)alloc((size_t)N * KDIM * 4);
    int*   deg4    = (int*)alloc((size_t)N * 4 * 4);
    int*   adj     = (int*)alloc((size_t)N * 4 * CAPS * 4);

    int qchunks = N * QDIM / 4;   // float4 chunks of query
    int total2 = qchunks + 128 * QDIM + 128 * KDIM + 4 * N;   // linear-thread region
    int nblk = GBLK + (total2 + 255) / 256;
    prep_kernel<<<nblk, 256, 0, stream>>>(
        query, Qh, Pay, Wq, bq, Wk, bk, Wv, bv, Ws, bs, mask_idx, M,
        BhT, OBall, deg4, qchunks, N);

    int XA = (N + 63) / 64, XM = (M + 63) / 64;
    int NB = XA + 4 * XM + XM;    // V(157) + U(248) + S(62) = 467
    gemm_nodes<<<NB, 256, 0, stream>>>(Qh, key_idx, BhT, OBall, esrc, edst,
                                       mask_idx, M, deg4, adj, E,
                                       Ubuf, Pay, Sbuf, N, XA, XM);

    attend_out<<<(M + 3) / 4, 256, 0, stream>>>(Ubuf, Pay, Sbuf, deg4, adj,
                                                mask_idx, Wo, bo, (float*)d_out, M);
}

// Round 9
// 127.399 us; speedup vs baseline: 1.2077x; 1.0162x over previous
//
#include <hip/hip_runtime.h>

#define QDIM 192
#define KDIM 64
#define CDIM 256
#define DOUT 128
#define CAPS 32     // adjacency slots per sub-bucket; per-sub deg ~ Poisson(8), P(>=32) ~ 1.4e-9
#define NBCOL 384   // B virtual cols: [U 0:256 | V 256:320 | S 320:384]
#define NEG_INF __int_as_float(0xFF800000)
#define LDP 200     // LDS row pitch in halves (192 + 8 pad)
#define GBLK 4096   // wave-parallel G-region blocks (256 j x 64 wave-jobs / 4 waves per block)

typedef _Float16 hf2 __attribute__((ext_vector_type(2)));
typedef _Float16 half4 __attribute__((ext_vector_type(4)));
typedef _Float16 half8 __attribute__((ext_vector_type(8)));
typedef float floatx4 __attribute__((ext_vector_type(4)));

#if defined(__has_builtin)
#if __has_builtin(__builtin_amdgcn_fdot2)
#define HAVE_FDOT2 1
#endif
#endif

__device__ __forceinline__ hf2 bc_h2(unsigned u) { return __builtin_bit_cast(hf2, u); }

__device__ __forceinline__ float dot2acc(hf2 a, hf2 b, float c) {
#ifdef HAVE_FDOT2
    return __builtin_amdgcn_fdot2(a, b, c, false);
#else
    return c + (float)a[0] * (float)b[0] + (float)a[1] * (float)b[1];
#endif
}

__device__ __forceinline__ float wave_sum(float p) {
    p += __shfl_xor(p, 1, 64);
    p += __shfl_xor(p, 2, 64);
    p += __shfl_xor(p, 4, 64);
    p += __shfl_xor(p, 8, 64);
    p += __shfl_xor(p, 16, 64);
    p += __shfl_xor(p, 32, 64);
    return p;
}

// prep (R7 structure):
//  Region G (blocks [0, GBLK)): WAVE-PARALLEL dots along K.
//    sub<48:  GhT[j][sub*4 .. +4)   = fp16( Wq[i,:] . Wk[j,:] )
//    sub>=48: OBall[j][k0 .. +4)    = (Wq[192+ki,:]+bq) . Wk[j,:]   (f32)
//  Region T (linear threads after GBLK):
//    1) query fp32->fp16 into Qh AND Pay q-slots
//    2) direct BhT cols 256..383 from Wv/Ws cols 192..255
//    3) OBall direct (V,S): one-hot row + bias fused
//    4) deg4 init: ONE search per node, int4 store (0 masked / INT_MIN otherwise)
__global__ __launch_bounds__(256) void prep_kernel(
        const float* __restrict__ query, _Float16* __restrict__ Qh,
        _Float16* __restrict__ Pay,
        const float* __restrict__ Wq, const float* __restrict__ bq,
        const float* __restrict__ Wk, const float* __restrict__ bk,
        const float* __restrict__ Wv, const float* __restrict__ bv,
        const float* __restrict__ Ws, const float* __restrict__ bs,
        const int* __restrict__ mask, int M,
        _Float16* __restrict__ BhT, float* __restrict__ OBall,
        int* __restrict__ deg4, int qchunks, int N) {
    int blk = blockIdx.x;
    if (blk < GBLK) {
        int lane = threadIdx.x & 63;
        int gw = blk * 4 + (threadIdx.x >> 6);
        int j = gw >> 6, sub = gw & 63;
        float4 wk4 = ((const float4*)(Wk + (size_t)j * CDIM))[lane];
        if (sub < 48) {
            half4 h;
            #pragma unroll
            for (int r = 0; r < 4; r++) {
                int i = sub * 4 + r;
                float4 a = ((const float4*)(Wq + (size_t)i * CDIM))[lane];
                float p = a.x*wk4.x + a.y*wk4.y + a.z*wk4.z + a.w*wk4.w;
                h[r] = (_Float16)wave_sum(p);
            }
            if (lane == 0) *(half4*)(BhT + (size_t)j * QDIM + sub * 4) = h;
        } else {
            int k0 = (sub - 48) * 4;
            float rr[4];
            float4 b4 = ((const float4*)bq)[lane];
            #pragma unroll
            for (int r = 0; r < 4; r++) {
                int i = QDIM + k0 + r;
                float4 a = ((const float4*)(Wq + (size_t)i * CDIM))[lane];
                float p = (a.x+b4.x)*wk4.x + (a.y+b4.y)*wk4.y
                        + (a.z+b4.z)*wk4.z + (a.w+b4.w)*wk4.w;
                rr[r] = wave_sum(p);
            }
            if (lane == 0)
                *(float4*)(OBall + (size_t)j * KDIM + k0) = make_float4(rr[0], rr[1], rr[2], rr[3]);
        }
        return;
    }
    int t = (blk - GBLK) * 256 + threadIdx.x;
    if (t < qchunks) {
        float4 v = ((const float4*)query)[t];
        half4 h = { (_Float16)v.x, (_Float16)v.y, (_Float16)v.z, (_Float16)v.w };
        ((half4*)Qh)[t] = h;
        int h0 = t * 4;
        int src = h0 / QDIM, i = h0 - src * QDIM;   // i%12 in {0,4,8}: no chunk straddle
        *(half4*)(Pay + (size_t)src * 256 + (i / 12) * 16 + (i % 12)) = h;
        return;
    }
    t -= qchunks;
    if (t < 128 * QDIM) {                // direct BhT (V,S)
        int c = t / QDIM, r = t - c * QDIM;
        float val = (c < 64) ? Wv[(size_t)r * CDIM + QDIM + c]
                             : Ws[(size_t)r * CDIM + QDIM + (c - 64)];
        BhT[(size_t)(256 + c) * QDIM + r] = (_Float16)val;
        return;
    }
    t -= 128 * QDIM;
    if (t < 128 * KDIM) {                // OBall direct (V,S)
        int jj = t >> 6, ki = t & 63;
        const float* Wseg; const float* bseg; int col;
        if (jj < 64) { Wseg = Wv; bseg = bv; col = QDIM + jj; }
        else         { Wseg = Ws; bseg = bs; col = QDIM + (jj - 64); }
        OBall[(size_t)(256 + jj) * KDIM + ki] =
            Wseg[(size_t)(QDIM + ki) * CDIM + col] + bseg[col];
        return;
    }
    t -= 128 * KDIM;
    if (t < N) {                         // deg4 init: 1 search/node, int4 store
        int lo = 0, hi = M;
        while (lo < hi) { int mid = (lo + hi) >> 1; if (mask[mid] < t) lo = mid + 1; else hi = mid; }
        bool found = (lo < M) && (mask[lo] == t);
        int v = found ? 0 : (int)0x80000000;
        ((int4*)deg4)[t] = make_int4(v, v, v, v);
    }
}

// MFMA node GEMM over the reduced col space [U|V|S], 3 block classes:
//  cls 0 (V):  all rows, bn=256 -> Pay v-slots          (157 blocks)
//  cls 1 (U):  masked rows, bn in {0,64,128,192} -> Ubuf (248 blocks)
//  cls 2 (S):  masked rows, bn=320 -> Sbuf               (62 blocks)
// All blocks carry 3 gated edge-scatter slots (atomic post-barrier, adj write
// post-MFMA); adj entry packs (src<<6)|key_idx[src].
__global__ __launch_bounds__(256) void gemm_nodes(
        const _Float16* __restrict__ Qh, const int* __restrict__ key_idx,
        const _Float16* __restrict__ BhT, const float* __restrict__ OBall,
        const int* __restrict__ esrc, const int* __restrict__ edst,
        const int* __restrict__ mask, int M,
        int* deg4, int* __restrict__ adj, int E,
        _Float16* __restrict__ Ubuf, _Float16* __restrict__ Pay,
        float* __restrict__ Sbuf, int N, int XA, int XM) {
    __shared__ __align__(16) _Float16 Bs[64 * LDP];
    int tid = threadIdx.x;
    int b = blockIdx.x;
    int cls, rb, bn;
    if (b < XA)                 { cls = 0; rb = b;                bn = 256; }
    else if (b < XA + 4 * XM)   { int u2 = b - XA; cls = 1; rb = u2 >> 2; bn = (u2 & 3) * 64; }
    else                        { cls = 2; rb = b - XA - 4 * XM;  bn = 320; }
    int bm = rb * 64;

    // scatter duty: 3 gated edge slots (mask-skip via deg4 sign)
    bool doe[3] = {false, false, false};
    int srcv[3]; size_t ci[3] = {0, 0, 0};
    {
        int stride = gridDim.x * 256;
        int base = b * 256 + tid;
        #pragma unroll
        for (int q = 0; q < 3; q++) {
            int e = base + q * stride;
            if (e < E) {
                int d = edst[e];
                size_t c = (size_t)d * 4 + (e & 3);
                if (deg4[c] >= 0) {
                    doe[q] = true;
                    int s = esrc[e];
                    srcv[q] = (s << 6) | (key_idx[s] & 63);
                    ci[q] = c;
                }
            }
        }
    }

    int w = tid >> 6, l = tid & 63;
    int lrow = l & 15, quad = l >> 4;

    // A fragments direct from global (issued pre-barrier; drain during Bs staging)
    int ra = w * 16 + lrow;
    int gra = (cls == 0) ? min(bm + ra, N - 1) : mask[min(bm + ra, M - 1)];
    const _Float16* abase = Qh + (size_t)gra * QDIM + quad * 8;
    half8 af[6];
    #pragma unroll
    for (int ks = 0; ks < 6; ks++) af[ks] = *(const half8*)(abase + ks * 32);

    // B tile: 64 cols x 192 halves = 1536 uint4; 6 per thread
    #pragma unroll
    for (int it = 0; it < 6; it++) {
        int idx = tid + it * 256;
        int cc = idx / 24, q4 = idx % 24;
        uint4 vb = ((const uint4*)(BhT + (size_t)(bn + cc) * QDIM))[q4];
        *((uint4*)&Bs[cc * LDP + q4 * 8]) = vb;
    }
    __syncthreads();

    // contended atomics now; latency hides under ds_read+MFMA below
    int slot[3] = {-1, -1, -1};
    #pragma unroll
    for (int q = 0; q < 3; q++) if (doe[q]) slot[q] = atomicAdd(&deg4[ci[q]], 1);

    floatx4 acc[4] = {{0.f,0.f,0.f,0.f},{0.f,0.f,0.f,0.f},{0.f,0.f,0.f,0.f},{0.f,0.f,0.f,0.f}};
    #pragma unroll
    for (int ks = 0; ks < 6; ks++) {
        #pragma unroll
        for (int nt = 0; nt < 4; nt++) {
            half8 bf = *(const half8*)(&Bs[(nt * 16 + lrow) * LDP + quad * 8 + ks * 32]);
            acc[nt] = __builtin_amdgcn_mfma_f32_16x16x32_f16(af[ks], bf, acc[nt], 0, 0, 0);
        }
    }

    // consume atomic results only now (waitcnt lands after the MFMAs)
    #pragma unroll
    for (int q = 0; q < 3; q++)
        if (doe[q] && (unsigned)slot[q] < CAPS) adj[ci[q] * CAPS + slot[q]] = srcv[q];

    // epilogue: clamped/duplicate rows write identical values (benign)
    int ki[4], grs[4];
    #pragma unroll
    for (int reg = 0; reg < 4; reg++) {
        int re = w * 16 + quad * 4 + reg;
        grs[reg] = (cls == 0) ? min(bm + re, N - 1) : mask[min(bm + re, M - 1)];
        ki[reg] = key_idx[grs[reg]];
    }
    #pragma unroll
    for (int nt = 0; nt < 4; nt++) {
        int gc = bn + nt * 16 + lrow;
        const float* obc = OBall + (size_t)gc * KDIM;
        #pragma unroll
        for (int reg = 0; reg < 4; reg++) {
            int gr = grs[reg];
            float v = acc[nt][reg] + obc[ki[reg]];
            if (gc < 256)      Ubuf[(size_t)gr * 256 + gc] = (_Float16)v;
            else if (gc < 320) { int c = gc - 256;
                                 Pay[(size_t)gr * 256 + (c >> 2) * 16 + 12 + (c & 3)] = (_Float16)v; }
            else               Sbuf[(size_t)gr * KDIM + (gc - 320)] = v;
        }
    }
}

// 1 wave per output-run (masked node). score = (u.x_s)/16 with the dst-constant
// terms dropped (softmax-invariant): per edge, ONE payload gather (2x uint4,
// interleaved q|v) + tiny per-node lut read u[192+ks] (256B, L1). 4 sub-buckets
// walked as one concatenated list round-robin (balanced); 2-deep register
// pipeline; online softmax per group; single end-merge; fused relu + GEMV.
__global__ __launch_bounds__(256) void attend_out(
        const _Float16* __restrict__ Ubuf, const _Float16* __restrict__ Pay,
        const float* __restrict__ Sbuf,
        const int* __restrict__ deg4, const int* __restrict__ adj,
        const int* __restrict__ mask, const float* __restrict__ Wo,
        const float* __restrict__ bo, float* __restrict__ out, int M) {
    int w = threadIdx.x >> 6, lane = threadIdx.x & 63;
    int r = blockIdx.x * 4 + w;
    if (r >= M) return;
    int node = mask[r];
    if (r > 0 && mask[r - 1] == node) return;   // duplicate run: start-wave writes it
    int l = lane & 15, g = lane >> 4;

    // u fragment: halves [l*12, l*12+12)
    const uint2* up = (const uint2*)(Ubuf + (size_t)node * 256 + l * 12);
    uint2 u0 = up[0], u1 = up[1], u2 = up[2];
    hf2 uf[6] = { bc_h2(u0.x), bc_h2(u0.y), bc_h2(u1.x),
                  bc_h2(u1.y), bc_h2(u2.x), bc_h2(u2.y) };
    const _Float16* lutp = Ubuf + (size_t)node * 256 + QDIM;

    // concatenated-list geometry over 4 sub-buckets
    int dn_g = min(deg4[(size_t)node * 4 + g], CAPS);
    int d0 = __shfl(dn_g, 0, 64), d1 = __shfl(dn_g, 16, 64);
    int d2 = __shfl(dn_g, 32, 64), d3 = __shfl(dn_g, 48, 64);
    int O1 = d0, O2 = d0 + d1, O3 = d0 + d1 + d2, T = O3 + d3;
    const size_t base4 = (size_t)node * 4 * CAPS;
    auto fs = [&](int j) -> int {
        int b = (j >= O1) + (j >= O2) + (j >= O3);
        int off = j - (b == 0 ? 0 : b == 1 ? O1 : b == 2 ? O2 : O3);
        return adj[base4 + (size_t)b * CAPS + off];   // packed (src<<6)|ks
    };
    auto idxAt = [&](int p) -> int { return fs(min(g + 4 * p, T - 1)); };

    float m = NEG_INF, dsum = 0.f;
    float a0 = 0.f, a1 = 0.f, a2 = 0.f, a3 = 0.f;

    auto compute = [&](uint4 A0, uint4 A1, float lut) {
        float d = 0.f;
        d = dot2acc(bc_h2(A0.x), uf[0], d);
        d = dot2acc(bc_h2(A0.y), uf[1], d);
        d = dot2acc(bc_h2(A0.z), uf[2], d);
        d = dot2acc(bc_h2(A0.w), uf[3], d);
        d = dot2acc(bc_h2(A1.x), uf[4], d);
        d = dot2acc(bc_h2(A1.y), uf[5], d);
        d += __shfl_xor(d, 1, 64);
        d += __shfl_xor(d, 2, 64);
        d += __shfl_xor(d, 4, 64);
        d += __shfl_xor(d, 8, 64);
        float sc = (d + lut) * 0.0625f;      // 1/sqrt(256); dst-const terms dropped
        float m_new = fmaxf(m, sc);
        float scale = __expf(m - m_new);     // first edge: exp(-inf)=0
        float p = __expf(sc - m_new);
        dsum = dsum * scale + p;
        hf2 v01 = bc_h2(A1.z), v23 = bc_h2(A1.w);
        a0 = a0 * scale + p * (float)v01[0];
        a1 = a1 * scale + p * (float)v01[1];
        a2 = a2 * scale + p * (float)v23[0];
        a3 = a3 * scale + p * (float)v23[1];
        m = m_new;
    };

    int np = (g < T) ? ((T - g + 3) >> 2) : 0;   // positions for this group
    uint4 A0 = {}, A1 = {}, B0 = {}, B1 = {};
    float lutA = 0.f, lutB = 0.f;
    int vC = 0, vD = 0;
    if (np > 0) {
        int vA = idxAt(0);
        const uint4* pp = (const uint4*)(Pay + (size_t)(vA >> 6) * 256 + l * 16);
        A0 = pp[0]; A1 = pp[1];
        lutA = (float)lutp[vA & 63];
        int vB = idxAt(1);
        const uint4* pb = (const uint4*)(Pay + (size_t)(vB >> 6) * 256 + l * 16);
        B0 = pb[0]; B1 = pb[1];
        lutB = (float)lutp[vB & 63];
        vC = idxAt(2); vD = idxAt(3);
    }
    for (int p = 0; p < np; p += 2) {
        compute(A0, A1, lutA);                 // position p
        {   // refill A <- position p+2 (clamped-valid speculative load)
            const uint4* pp = (const uint4*)(Pay + (size_t)(vC >> 6) * 256 + l * 16);
            A0 = pp[0]; A1 = pp[1];
            lutA = (float)lutp[vC & 63];
        }
        int vC2 = idxAt(p + 4);
        if (p + 1 < np) compute(B0, B1, lutB); // position p+1
        {   // refill B <- position p+3
            const uint4* pb = (const uint4*)(Pay + (size_t)(vD >> 6) * 256 + l * 16);
            B0 = pb[0]; B1 = pb[1];
            lutB = (float)lutp[vD & 63];
        }
        int vD2 = idxAt(p + 5);
        vC = vC2; vD = vD2;
    }

    // merge the 4 groups (m, dsum group-uniform)
    float Mx = fmaxf(m, __shfl_xor(m, 16, 64));
    Mx = fmaxf(Mx, __shfl_xor(Mx, 32, 64));
    float wgt = (m == NEG_INF) ? 0.f : __expf(m - Mx);   // empty group / T==0
    float ds = dsum * wgt;
    ds += __shfl_xor(ds, 16, 64);
    ds += __shfl_xor(ds, 32, 64);
    a0 *= wgt; a1 *= wgt; a2 *= wgt; a3 *= wgt;
    a0 += __shfl_xor(a0, 16, 64); a0 += __shfl_xor(a0, 32, 64);
    a1 += __shfl_xor(a1, 16, 64); a1 += __shfl_xor(a1, 32, 64);
    a2 += __shfl_xor(a2, 16, 64); a2 += __shfl_xor(a2, 32, 64);
    a3 += __shfl_xor(a3, 16, 64); a3 += __shfl_xor(a3, 32, 64);
    float inv = 1.f / (ds + 1e-16f);

    // h cols l*4..l*4+3 (identical across groups)
    float4 s4 = *((const float4*)(Sbuf + (size_t)node * KDIM + l * 4));
    float h0 = fmaxf(a0 * inv + s4.x, 0.f);
    float h1 = fmaxf(a1 * inv + s4.y, 0.f);
    float h2 = fmaxf(a2 * inv + s4.z, 0.f);
    float h3 = fmaxf(a3 * inv + s4.w, 0.f);

    // GEMV: out(row) = h @ Wo + bo
    float o0 = bo[lane], o1 = bo[lane + 64];
    #pragma unroll
    for (int c = 0; c < KDIM; c++) {
        float hc = (c & 3) == 0 ? h0 : (c & 3) == 1 ? h1 : (c & 3) == 2 ? h2 : h3;
        float hv = __shfl(hc, c >> 2, 64);
        o0 += hv * Wo[c * DOUT + lane];
        o1 += hv * Wo[c * DOUT + 64 + lane];
    }
    int rr = r;
    do {
        out[(size_t)rr * DOUT + lane] = o0;
        out[(size_t)rr * DOUT + 64 + lane] = o1;
        rr++;
    } while (rr < M && mask[rr] == node);
}

extern "C" void kernel_launch(void* const* d_in, const int* in_sizes, int n_in,
                              void* d_out, int out_size, void* d_ws, size_t ws_size,
                              hipStream_t stream) {
    const float* query    = (const float*)d_in[0];
    const int* key_idx    = (const int*)d_in[1];
    const int* edge_index = (const int*)d_in[2];
    const int* mask_idx   = (const int*)d_in[3];
    const float* Wq = (const float*)d_in[4];
    const float* bq = (const float*)d_in[5];
    const float* Wk = (const float*)d_in[6];
    const float* bk = (const float*)d_in[7];
    const float* Wv = (const float*)d_in[8];
    const float* bv = (const float*)d_in[9];
    const float* Ws = (const float*)d_in[10];
    const float* bs = (const float*)d_in[11];
    const float* Wo = (const float*)d_in[12];
    const float* bo = (const float*)d_in[13];
    (void)bk;   // bk folds out: its dst-side terms are softmax-invariant

    int N = in_sizes[0] / QDIM;
    int E = in_sizes[2] / 2;
    int M = in_sizes[3];
    const int* esrc = edge_index;
    const int* edst = edge_index + E;

    char* wsb = (char*)d_ws;
    size_t off = 0;
    auto alloc = [&](size_t nbytes) { char* p = wsb + off; off += (nbytes + 15) & ~15ull; return p; };
    _Float16* Qh   = (_Float16*)alloc((size_t)N * QDIM * 2);
    _Float16* Pay  = (_Float16*)alloc((size_t)N * 256 * 2);
    _Float16* Ubuf = (_Float16*)alloc((size_t)N * 256 * 2);
    _Float16* BhT  = (_Float16*)alloc((size_t)NBCOL * QDIM * 2);
    float* OBall   = (float*)alloc((size_t)NBCOL * KDIM * 4);
    float* Sbuf    = (float*)alloc((size_t)N * KDIM * 4);
    int*   deg4    = (int*)alloc((size_t)N * 4 * 4);
    int*   adj     = (int*)alloc((size_t)N * 4 * CAPS * 4);

    int qchunks = N * QDIM / 4;   // float4 chunks of query
    int total2 = qchunks + 128 * QDIM + 128 * KDIM + N;   // linear-thread region
    int nblk = GBLK + (total2 + 255) / 256;
    prep_kernel<<<nblk, 256, 0, stream>>>(
        query, Qh, Pay, Wq, bq, Wk, bk, Wv, bv, Ws, bs, mask_idx, M,
        BhT, OBall, deg4, qchunks, N);

    int XA = (N + 63) / 64, XM = (M + 63) / 64;
    int NB = XA + 4 * XM + XM;    // V(157) + U(248) + S(62) = 467
    gemm_nodes<<<NB, 256, 0, stream>>>(Qh, key_idx, BhT, OBall, esrc, edst,
                                       mask_idx, M, deg4, adj, E,
                                       Ubuf, Pay, Sbuf, N, XA, XM);

    attend_out<<<(M + 3) / 4, 256, 0, stream>>>(Ubuf, Pay, Sbuf, deg4, adj,
                                                mask_idx, Wo, bo, (float*)d_out, M);
}